// Round 3
// baseline (525.283 us; speedup 1.0000x reference)
//
#include <hip/hip_runtime.h>
#include <stdint.h>

typedef unsigned short u16;
typedef __attribute__((ext_vector_type(8))) short short8;
typedef __attribute__((ext_vector_type(4))) float floatx4;

#define MFMA16(a, b, c) __builtin_amdgcn_mfma_f32_16x16x32_bf16(a, b, c, 0, 0, 0)

static __device__ __forceinline__ void gl_lds16(const void* g, void* l) {
  __builtin_amdgcn_global_load_lds(
      (const __attribute__((address_space(1))) uint32_t*)g,
      (__attribute__((address_space(3))) uint32_t*)l, 16, 0, 0);
}

static __device__ __forceinline__ float b2f(u16 u) {
  union { float f; unsigned u; } v;
  v.u = ((unsigned)u) << 16;
  return v.f;
}
static __device__ __forceinline__ u16 f2b(float f) {
  union { float f; unsigned u; } v;
  v.f = f;
  unsigned r = v.u + 0x7fffu + ((v.u >> 16) & 1u);  // RNE
  return (u16)(r >> 16);
}

// DPP row-rotate reductions over 16-lane groups (VALU, no LDS traffic).
template <int CTRL>
static __device__ __forceinline__ float dppf(float x) {
  return __builtin_bit_cast(
      float, __builtin_amdgcn_update_dpp(0, __builtin_bit_cast(int, x), CTRL,
                                         0xF, 0xF, true));
}
static __device__ __forceinline__ float sum16(float x) {
  x += dppf<0x128>(x);
  x += dppf<0x124>(x);
  x += dppf<0x122>(x);
  x += dppf<0x121>(x);
  return x;
}
static __device__ __forceinline__ float max16(float x) {
  x = fmaxf(x, dppf<0x128>(x));
  x = fmaxf(x, dppf<0x124>(x));
  x = fmaxf(x, dppf<0x122>(x));
  x = fmaxf(x, dppf<0x121>(x));
  return x;
}

// ---------------------------------------------------------------------------
// Input-dtype detector (f32 vs bf16).
// ---------------------------------------------------------------------------
__global__ __launch_bounds__(256) void detect_f32(const u16* __restrict__ x,
                                                  int* __restrict__ flag) {
  __shared__ int cnt[256];
  int c = 0;
  for (int i = threadIdx.x; i < 65536; i += 256) {
    int e = (x[i] >> 7) & 0xFF;
    if (e >= 140) ++c;
  }
  cnt[threadIdx.x] = c;
  __syncthreads();
  for (int s = 128; s > 0; s >>= 1) {
    if (threadIdx.x < (unsigned)s) cnt[threadIdx.x] += cnt[threadIdx.x + s];
    __syncthreads();
  }
  if (threadIdx.x == 0) *flag = (cnt[0] > 1000) ? 1 : 0;
}

// Vectorized flag-aware convert: 8 elems/thread.
__global__ __launch_bounds__(256) void convert_in8(const void* __restrict__ src,
                                                   u16* __restrict__ dst, int n8,
                                                   const int* __restrict__ flag) {
  int i = blockIdx.x * 256 + threadIdx.x;
  if (i >= n8) return;
  short8 r;
  if (*flag) {
    const float4* s = (const float4*)src;
    float4 a = s[2 * i], b = s[2 * i + 1];
    r[0] = (short)f2b(a.x); r[1] = (short)f2b(a.y);
    r[2] = (short)f2b(a.z); r[3] = (short)f2b(a.w);
    r[4] = (short)f2b(b.x); r[5] = (short)f2b(b.y);
    r[6] = (short)f2b(b.z); r[7] = (short)f2b(b.w);
  } else {
    r = ((const short8*)src)[i];
  }
  ((short8*)dst)[i] = r;
}

__global__ __launch_bounds__(256) void transpose_conv(const void* __restrict__ in,
                                                      u16* __restrict__ out,
                                                      int R, int Ccols,
                                                      const int* __restrict__ flag) {
  __shared__ u16 tile[32][33];
  int f = *flag;
  int c0 = blockIdx.x * 32, r0 = blockIdx.y * 32;
  int lx = threadIdx.x & 31, ly = threadIdx.x >> 5;
#pragma unroll
  for (int i = 0; i < 32; i += 8) {
    size_t idx = (size_t)(r0 + ly + i) * Ccols + c0 + lx;
    tile[ly + i][lx] = f ? f2b(((const float*)in)[idx]) : ((const u16*)in)[idx];
  }
  __syncthreads();
#pragma unroll
  for (int i = 0; i < 32; i += 8)
    out[(size_t)(c0 + ly + i) * R + r0 + lx] = tile[lx][ly + i];
}

// V half of KV [4096][4096] -> Vt[b][d][s]  ([2][2048][2048])
__global__ __launch_bounds__(256) void transpose_v(const u16* __restrict__ KV,
                                                   u16* __restrict__ Vt) {
  __shared__ u16 tile[32][33];
  int b = blockIdx.z;
  int d0 = blockIdx.x * 32, s0 = blockIdx.y * 32;
  int lx = threadIdx.x & 31, ly = threadIdx.x >> 5;
  const u16* src = KV + ((size_t)(b * 2048 + s0)) * 4096 + 2048 + d0;
#pragma unroll
  for (int i = 0; i < 32; i += 8)
    tile[ly + i][lx] = src[(size_t)(ly + i) * 4096 + lx];
  __syncthreads();
  u16* dst = Vt + ((size_t)(b * 2048 + d0)) * 2048 + s0;
#pragma unroll
  for (int i = 0; i < 32; i += 8)
    dst[(size_t)(ly + i) * 2048 + lx] = tile[lx][ly + i];
}

// ---------------------------------------------------------------------------
// 8-phase 256x256 NT GEMM (learn_hip m201 template, adapted to NT layout).
// 512 thr = 8 waves (2M x 4N); per-wave 128x64 out = acc[8][4]; BK=64.
// LDS 128 KiB: 2 dbuf x (A 256x64 + B 256x64) bf16, row-XOR chunk swizzle
// (proven conflict-free in prior gemm_nt: SQ_LDS_BANK_CONFLICT == 0).
// Per K-tile 4 phases x 16 MFMA; one half-tile (128 rows, 2 gl_lds) staged
// per phase; stage order [B0,B1,A0,A1] so each staged region is dead >=1
// barrier earlier (B read only at P0; A reads end P2; A0@P3, A1@next P0).
// vmcnt(6) at tile top only (issued 14+8t, consumed 8t+8 -> exactly 6 in
// flight); tail stages clamp tau to NT-1 to keep counts exact.
// ---------------------------------------------------------------------------
__global__ __launch_bounds__(512, 2) void gemm8(const u16* __restrict__ A,
                                                const u16* __restrict__ Bm,
                                                void* __restrict__ Cv,
                                                int M, int N, int K,
                                                const int* __restrict__ flag,
                                                int flag_mode) {
  __shared__ u16 Ash[2 * 256 * 64];
  __shared__ u16 Bsh[2 * 256 * 64];
  int tid = threadIdx.x, w = tid >> 6, lane = tid & 63;
  int quad = lane >> 4, l15 = lane & 15;
  int wr = w >> 2, wc = w & 3;
  int wm = wr * 128, wn = wc * 64;
  int m0 = blockIdx.y * 256, n0 = blockIdx.x * 256;
  int f32out = flag_mode ? *flag : 0;
  const int NT = K >> 6;

  int srow8 = lane >> 3;
  int gch = (lane & 7) ^ srow8;
  const u16* Ag = A + (size_t)(m0 + w * 8 + srow8) * K + gch * 8;
  const u16* Bg = Bm + (size_t)(n0 + w * 8 + srow8) * K + gch * 8;
  int ldsrow = w * 8;  // wave-uniform LDS row base; lane*16B added by HW

  floatx4 acc[8][4];
#pragma unroll
  for (int i = 0; i < 8; ++i)
#pragma unroll
    for (int j = 0; j < 4; ++j) acc[i][j] = floatx4{0.f, 0.f, 0.f, 0.f};

  int ch0 = ((quad ^ (l15 & 7)) << 3);        // kk=0 chunk byte-> u16 offset
  int ch1 = (((4 + quad) ^ (l15 & 7)) << 3);  // kk=1

  auto stage = [&](int qi) {
    int tau = qi >> 2;
    int tc = tau < NT ? tau : NT - 1;  // clamp keeps vmcnt counts exact
    int hh = qi & 3;                   // 0:B0 1:B1 2:A0 3:A1
    int half = (hh & 1) * 128;
    int sbuf = (tau & 1) * (256 * 64);
    size_t kof = (size_t)tc * 64;
    if (hh < 2) {
      gl_lds16(Bg + (size_t)half * K + kof,
               (void*)(Bsh + sbuf + (half + ldsrow) * 64));
      gl_lds16(Bg + (size_t)(half + 64) * K + kof,
               (void*)(Bsh + sbuf + (half + 64 + ldsrow) * 64));
    } else {
      gl_lds16(Ag + (size_t)half * K + kof,
               (void*)(Ash + sbuf + (half + ldsrow) * 64));
      gl_lds16(Ag + (size_t)(half + 64) * K + kof,
               (void*)(Ash + sbuf + (half + 64 + ldsrow) * 64));
    }
  };

  // Prologue: tile0 fully + 3 half-tiles of tile1 -> 3 half-tiles in flight.
  stage(0); stage(1); stage(2); stage(3);
  __asm__ volatile("s_waitcnt vmcnt(4)" ::: "memory");
  stage(4); stage(5); stage(6);
  __asm__ volatile("s_waitcnt vmcnt(6)" ::: "memory");
  __builtin_amdgcn_s_barrier();

  for (int t = 0; t < NT; ++t) {
    u16* As = Ash + (t & 1) * (256 * 64);
    u16* Bs = Bsh + (t & 1) * (256 * 64);
    if (t) {
      __asm__ volatile("s_waitcnt vmcnt(6)" ::: "memory");
      __builtin_amdgcn_s_barrier();
    }
    int qb = 7 + 4 * t;
    short8 bf[8], af0[8], af1[8];

    // ---- P0: read all B frags + A-mh0; MFMA (mh0 x j01) ----
#pragma unroll
    for (int j = 0; j < 4; ++j) {
      int n = wn + 16 * j + l15;
      bf[2 * j] = *(const short8*)(Bs + n * 64 + ch0);
      bf[2 * j + 1] = *(const short8*)(Bs + n * 64 + ch1);
    }
#pragma unroll
    for (int i = 0; i < 4; ++i) {
      int m = wm + 16 * i + l15;
      af0[2 * i] = *(const short8*)(As + m * 64 + ch0);
      af0[2 * i + 1] = *(const short8*)(As + m * 64 + ch1);
    }
    stage(qb);
    __builtin_amdgcn_s_barrier();
    __asm__ volatile("s_waitcnt lgkmcnt(0)" ::: "memory");
    __builtin_amdgcn_sched_barrier(0);
    __builtin_amdgcn_s_setprio(1);
#pragma unroll
    for (int i = 0; i < 4; ++i)
#pragma unroll
      for (int j = 0; j < 2; ++j) {
        acc[i][j] = MFMA16(af0[2 * i], bf[2 * j], acc[i][j]);
        acc[i][j] = MFMA16(af0[2 * i + 1], bf[2 * j + 1], acc[i][j]);
      }
    __builtin_amdgcn_s_setprio(0);
    __builtin_amdgcn_s_barrier();

    // ---- P1: read A-mh1 kk0; MFMA (mh0 x j23) ----
#pragma unroll
    for (int i = 0; i < 4; ++i) {
      int m = wm + 64 + 16 * i + l15;
      af1[2 * i] = *(const short8*)(As + m * 64 + ch0);
    }
    stage(qb + 1);
    __builtin_amdgcn_s_barrier();
    __asm__ volatile("s_waitcnt lgkmcnt(0)" ::: "memory");
    __builtin_amdgcn_sched_barrier(0);
    __builtin_amdgcn_s_setprio(1);
#pragma unroll
    for (int i = 0; i < 4; ++i)
#pragma unroll
      for (int j = 2; j < 4; ++j) {
        acc[i][j] = MFMA16(af0[2 * i], bf[2 * j], acc[i][j]);
        acc[i][j] = MFMA16(af0[2 * i + 1], bf[2 * j + 1], acc[i][j]);
      }
    __builtin_amdgcn_s_setprio(0);
    __builtin_amdgcn_s_barrier();

    // ---- P2: read A-mh1 kk1; MFMA (mh1 x j01) ----
#pragma unroll
    for (int i = 0; i < 4; ++i) {
      int m = wm + 64 + 16 * i + l15;
      af1[2 * i + 1] = *(const short8*)(As + m * 64 + ch1);
    }
    stage(qb + 2);
    __builtin_amdgcn_s_barrier();
    __asm__ volatile("s_waitcnt lgkmcnt(0)" ::: "memory");
    __builtin_amdgcn_sched_barrier(0);
    __builtin_amdgcn_s_setprio(1);
#pragma unroll
    for (int i = 0; i < 4; ++i)
#pragma unroll
      for (int j = 0; j < 2; ++j) {
        acc[4 + i][j] = MFMA16(af1[2 * i], bf[2 * j], acc[4 + i][j]);
        acc[4 + i][j] = MFMA16(af1[2 * i + 1], bf[2 * j + 1], acc[4 + i][j]);
      }
    __builtin_amdgcn_s_setprio(0);
    __builtin_amdgcn_s_barrier();

    // ---- P3: no reads; MFMA (mh1 x j23) ----
    stage(qb + 3);
    __builtin_amdgcn_s_barrier();
    __builtin_amdgcn_s_setprio(1);
#pragma unroll
    for (int i = 0; i < 4; ++i)
#pragma unroll
      for (int j = 2; j < 4; ++j) {
        acc[4 + i][j] = MFMA16(af1[2 * i], bf[2 * j], acc[4 + i][j]);
        acc[4 + i][j] = MFMA16(af1[2 * i + 1], bf[2 * j + 1], acc[4 + i][j]);
      }
    __builtin_amdgcn_s_setprio(0);
    __builtin_amdgcn_s_barrier();
  }

  // Epilogue (same C/D mapping as proven gemm_nt).
#pragma unroll
  for (int i = 0; i < 8; ++i)
#pragma unroll
    for (int r = 0; r < 4; ++r) {
      int row = m0 + wm + 16 * i + quad * 4 + r;
      if (f32out) {
        float* cp = (float*)Cv + (size_t)row * N + n0 + wn + l15;
#pragma unroll
        for (int j = 0; j < 4; ++j) cp[16 * j] = acc[i][j][r];
      } else {
        u16* cp = (u16*)Cv + (size_t)row * N + n0 + wn + l15;
#pragma unroll
        for (int j = 0; j < 4; ++j) cp[16 * j] = f2b(acc[i][j][r]);
      }
    }
}

// ---------------------------------------------------------------------------
// RoPE in-place; Q additionally scaled by 1/sqrt(dh) (folded from attention).
// ---------------------------------------------------------------------------
__global__ __launch_bounds__(256) void rope_kernel(u16* __restrict__ Q,
                                                   u16* __restrict__ KV) {
  const float scale = 0.08838834764831845f;  // 1/sqrt(128)
  int idx = blockIdx.x * 256 + threadIdx.x;
  int tok = idx >> 10;
  int rem = idx & 1023;
  int h = rem >> 6, i = rem & 63;
  int pos = tok & 2047;
  float f = __powf(10000.0f, -(float)(2 * i) * (1.0f / 128.0f));
  float ang = (float)pos * f;
  float s, c;
  sincosf(ang, &s, &c);

  size_t qb = (size_t)tok * 2048 + h * 128 + i;
  float q1 = b2f(Q[qb]), q2 = b2f(Q[qb + 64]);
  Q[qb] = f2b((q1 * c - q2 * s) * scale);
  Q[qb + 64] = f2b((q2 * c + q1 * s) * scale);

  size_t kb = (size_t)tok * 4096 + h * 128 + i;
  float k1 = b2f(KV[kb]), k2 = b2f(KV[kb + 64]);
  KV[kb] = f2b(k1 * c - k2 * s);
  KV[kb + 64] = f2b(k2 * c + k1 * s);
}

// ---------------------------------------------------------------------------
// Flash attention v5 (unchanged, proven): 512-thr blocks, 8 waves x 16 q-rows,
// grid 32 bh x 8 pairs; online softmax via DPP; swizzled gl_lds staging.
// ---------------------------------------------------------------------------
__global__ __launch_bounds__(512, 1) void flash_attn(const u16* __restrict__ Q,
                                                     const u16* __restrict__ KV,
                                                     const u16* __restrict__ Vt,
                                                     u16* __restrict__ O) {
  const int S = 2048, D = 2048, KVld = 4096;
  int bh = blockIdx.x;    // 0..31
  int pair = blockIdx.y;  // 0..7
  int b = bh >> 4, h = bh & 15;
  int tid = threadIdx.x, w = tid >> 6, lane = tid & 63;
  int quad = lane >> 4, l15 = lane & 15;

  const u16* Qb = Q + (size_t)(b * S) * D + h * 128;
  const u16* Kb = KV + (size_t)(b * S) * KVld + h * 128;
  const u16* Vtb = Vt + ((size_t)(b * 2048 + h * 128)) * S;

  __shared__ u16 Ksh[64 * 128];    // [krow][d], chunk ^= krow&7
  __shared__ u16 Vsh[128 * 64];    // [d][k],  chunk ^= d&7
  __shared__ u16 Psh[8][16 * 64];  // per-wave P, chunk ^= m&7

  for (int pi = 0; pi < 2; ++pi) {
    int qt = pi ? (15 - pair) : pair;
    int q0 = qt * 128;
    int qw = q0 + w * 16;  // this wave's 16 q-rows

    short8 qf[4];
    {
      const u16* qp = Qb + (size_t)(qw + l15) * D + quad * 8;
#pragma unroll
      for (int kk = 0; kk < 4; ++kk) qf[kk] = *(const short8*)(qp + kk * 32);
    }

    floatx4 o[8];
#pragma unroll
    for (int t = 0; t < 8; ++t) o[t] = floatx4{0.f, 0.f, 0.f, 0.f};
    float mrow[4], lrow[4];
#pragma unroll
    for (int r = 0; r < 4; ++r) { mrow[r] = -1e30f; lrow[r] = 0.f; }

    int nk = 2 * qt + 2;
    for (int kt = 0; kt < nk; ++kt) {
      int kb = kt * 64;
      __syncthreads();

      // stage K tile [64][128]: wave w -> rows [w*8, w*8+8), 2 instrs
#pragma unroll
      for (int tt = 0; tt < 2; ++tt) {
        int r0 = w * 8 + tt * 4;
        int row = r0 + quad;
        int g = (l15 & 8) | ((l15 & 7) ^ (row & 7));
        gl_lds16(Kb + (size_t)(kb + row) * KVld + g * 8, (void*)(Ksh + r0 * 128));
      }
      // stage V^T tile [128][64]: wave w -> d rows [w*16, w*16+16), 2 instrs
#pragma unroll
      for (int tt = 0; tt < 2; ++tt) {
        int d0 = w * 16 + tt * 8;
        int d = d0 + (lane >> 3);
        int g = (lane & 7) ^ (d & 7);
        gl_lds16(Vtb + (size_t)d * S + kb + g * 8, (void*)(Vsh + d0 * 64));
      }
      __syncthreads();

      if (kb <= qw + 15) {  // wave has at least one unmasked row
        // --- QK^T: 4n x 4ksteps = 16 MFMA ---
        floatx4 sc[4];
#pragma unroll
        for (int nf = 0; nf < 4; ++nf) sc[nf] = floatx4{0.f, 0.f, 0.f, 0.f};
#pragma unroll
        for (int kk = 0; kk < 4; ++kk) {
          int c = kk * 4 + quad;
          short8 kf[4];
#pragma unroll
          for (int nf = 0; nf < 4; ++nf) {
            int n = nf * 16 + l15;
            int pc = (c & 8) | ((c & 7) ^ (n & 7));
            kf[nf] = *(const short8*)(Ksh + n * 128 + pc * 8);
          }
#pragma unroll
          for (int nf = 0; nf < 4; ++nf) sc[nf] = MFMA16(qf[kk], kf[nf], sc[nf]);
        }

        // --- online softmax (1/sqrt(dh) pre-folded into Q) ---
        bool masked = (kb + 63 > qw);
        floatx4 alv;
#pragma unroll
        for (int r = 0; r < 4; ++r) {
          int qg = qw + quad * 4 + r;
          float v0 = sc[0][r], v1 = sc[1][r];
          float v2 = sc[2][r], v3 = sc[3][r];
          if (masked) {
            v0 = (kb + l15 <= qg) ? v0 : -1e30f;
            v1 = (kb + 16 + l15 <= qg) ? v1 : -1e30f;
            v2 = (kb + 32 + l15 <= qg) ? v2 : -1e30f;
            v3 = (kb + 48 + l15 <= qg) ? v3 : -1e30f;
          }
          float mx = max16(fmaxf(fmaxf(v0, v1), fmaxf(v2, v3)));
          float mn = fmaxf(mrow[r], mx);
          float al = __expf(mrow[r] - mn);
          mrow[r] = mn;
          float p0 = __expf(v0 - mn), p1 = __expf(v1 - mn);
          float p2 = __expf(v2 - mn), p3 = __expf(v3 - mn);
          float rs = sum16((p0 + p1) + (p2 + p3));
          lrow[r] = lrow[r] * al + rs;
          alv[r] = al;
          int m_ = quad * 4 + r, sw = m_ & 7;
          int cb = l15 >> 3, e = l15 & 7;
          u16* pr = Psh[w] + m_ * 64;
          pr[(((0 + cb) ^ sw) << 3) + e] = f2b(p0);
          pr[(((2 + cb) ^ sw) << 3) + e] = f2b(p1);
          pr[(((4 + cb) ^ sw) << 3) + e] = f2b(p2);
          pr[(((6 + cb) ^ sw) << 3) + e] = f2b(p3);
        }
#pragma unroll
        for (int t = 0; t < 8; ++t) o[t] *= alv;
        __asm__ volatile("s_waitcnt lgkmcnt(0)" ::: "memory");

        // --- PV: 8d x 2ksteps = 16 MFMA ---
#pragma unroll
        for (int ks = 0; ks < 2; ++ks) {
          int c = ks * 4 + quad;
          short8 pf = *(const short8*)(Psh[w] + l15 * 64 + ((c ^ (l15 & 7)) << 3));
#pragma unroll
          for (int t = 0; t < 8; ++t) {
            int d = t * 16 + l15;
            short8 vf = *(const short8*)(Vsh + d * 64 + ((c ^ (d & 7)) << 3));
            o[t] = MFMA16(pf, vf, o[t]);
          }
        }
      }
    }

    // epilogue
#pragma unroll
    for (int r = 0; r < 4; ++r) {
      float inv = 1.0f / lrow[r];
      int qg = qw + quad * 4 + r;
      u16* op = O + (size_t)(b * S + qg) * D + h * 128;
#pragma unroll
      for (int t = 0; t < 8; ++t) op[t * 16 + l15] = f2b(o[t][r] * inv);
    }
  }
}

// ---------------------------------------------------------------------------
// Launch. ws (u16 after 64-elem flag pad):
//   xb 8.4M | Wbuf 8.4M (wq -> wkvT -> Vt -> wo) | Qb 8.4M | KVb 16.8M
//   AO aliases xb. Total ~84 MB.
// ---------------------------------------------------------------------------
extern "C" void kernel_launch(void* const* d_in, const int* in_sizes, int n_in,
                              void* d_out, int out_size, void* d_ws, size_t ws_size,
                              hipStream_t stream) {
  const void* x = d_in[0];
  const void* wq = d_in[1];
  const void* wkv = d_in[2];
  const void* wo = d_in[3];

  int* flag = (int*)d_ws;
  u16* xb = (u16*)d_ws + 64;
  u16* Wbuf = xb + (size_t)8388608;
  u16* Qb = Wbuf + (size_t)8388608;
  u16* KVb = Qb + (size_t)8388608;
  u16* AO = xb;  // x dead after KV projection

  detect_f32<<<1, 256, 0, stream>>>((const u16*)x, flag);
  convert_in8<<<4096, 256, 0, stream>>>(x, xb, 1048576, flag);
  convert_in8<<<2048, 256, 0, stream>>>(wq, Wbuf, 524288, flag);
  gemm8<<<dim3(8, 16), 512, 0, stream>>>(xb, Wbuf, Qb, 4096, 2048, 2048, flag, 0);
  transpose_conv<<<dim3(128, 64), 256, 0, stream>>>(wkv, Wbuf, 2048, 4096, flag);
  gemm8<<<dim3(16, 16), 512, 0, stream>>>(xb, Wbuf, KVb, 4096, 4096, 2048, flag, 0);
  transpose_v<<<dim3(64, 64, 2), 256, 0, stream>>>(KVb, Wbuf);  // Wbuf := Vt
  rope_kernel<<<16384, 256, 0, stream>>>(Qb, KVb);
  flash_attn<<<dim3(32, 8), 512, 0, stream>>>(Qb, KVb, Wbuf, AO);
  convert_in8<<<2048, 256, 0, stream>>>(wo, Wbuf, 524288, flag);
  gemm8<<<dim3(8, 16), 512, 0, stream>>>(AO, Wbuf, d_out, 4096, 2048, 2048, flag, 1);
}

// Round 4
// 476.897 us; speedup vs baseline: 1.1015x; 1.1015x over previous
//
#include <hip/hip_runtime.h>
#include <stdint.h>

typedef unsigned short u16;
typedef __attribute__((ext_vector_type(8))) short short8;
typedef __attribute__((ext_vector_type(4))) float floatx4;

#define MFMA16(a, b, c) __builtin_amdgcn_mfma_f32_16x16x32_bf16(a, b, c, 0, 0, 0)

static __device__ __forceinline__ void gl_lds16(const void* g, void* l) {
  __builtin_amdgcn_global_load_lds(
      (const __attribute__((address_space(1))) uint32_t*)g,
      (__attribute__((address_space(3))) uint32_t*)l, 16, 0, 0);
}

static __device__ __forceinline__ float b2f(u16 u) {
  union { float f; unsigned u; } v;
  v.u = ((unsigned)u) << 16;
  return v.f;
}
static __device__ __forceinline__ u16 f2b(float f) {
  union { float f; unsigned u; } v;
  v.f = f;
  unsigned r = v.u + 0x7fffu + ((v.u >> 16) & 1u);  // RNE
  return (u16)(r >> 16);
}

// DPP row-rotate reductions over 16-lane groups (VALU, no LDS traffic).
template <int CTRL>
static __device__ __forceinline__ float dppf(float x) {
  return __builtin_bit_cast(
      float, __builtin_amdgcn_update_dpp(0, __builtin_bit_cast(int, x), CTRL,
                                         0xF, 0xF, true));
}
static __device__ __forceinline__ float sum16(float x) {
  x += dppf<0x128>(x);
  x += dppf<0x124>(x);
  x += dppf<0x122>(x);
  x += dppf<0x121>(x);
  return x;
}
static __device__ __forceinline__ float max16(float x) {
  x = fmaxf(x, dppf<0x128>(x));
  x = fmaxf(x, dppf<0x124>(x));
  x = fmaxf(x, dppf<0x122>(x));
  x = fmaxf(x, dppf<0x121>(x));
  return x;
}

// ---------------------------------------------------------------------------
// Input-dtype detector (f32 vs bf16).
// ---------------------------------------------------------------------------
__global__ __launch_bounds__(256) void detect_f32(const u16* __restrict__ x,
                                                  int* __restrict__ flag) {
  __shared__ int cnt[256];
  int c = 0;
  for (int i = threadIdx.x; i < 65536; i += 256) {
    int e = (x[i] >> 7) & 0xFF;
    if (e >= 140) ++c;
  }
  cnt[threadIdx.x] = c;
  __syncthreads();
  for (int s = 128; s > 0; s >>= 1) {
    if (threadIdx.x < (unsigned)s) cnt[threadIdx.x] += cnt[threadIdx.x + s];
    __syncthreads();
  }
  if (threadIdx.x == 0) *flag = (cnt[0] > 1000) ? 1 : 0;
}

// Vectorized flag-aware convert: 8 elems/thread.
__global__ __launch_bounds__(256) void convert_in8(const void* __restrict__ src,
                                                   u16* __restrict__ dst, int n8,
                                                   const int* __restrict__ flag) {
  int i = blockIdx.x * 256 + threadIdx.x;
  if (i >= n8) return;
  short8 r;
  if (*flag) {
    const float4* s = (const float4*)src;
    float4 a = s[2 * i], b = s[2 * i + 1];
    r[0] = (short)f2b(a.x); r[1] = (short)f2b(a.y);
    r[2] = (short)f2b(a.z); r[3] = (short)f2b(a.w);
    r[4] = (short)f2b(b.x); r[5] = (short)f2b(b.y);
    r[6] = (short)f2b(b.z); r[7] = (short)f2b(b.w);
  } else {
    r = ((const short8*)src)[i];
  }
  ((short8*)dst)[i] = r;
}

__global__ __launch_bounds__(256) void transpose_conv(const void* __restrict__ in,
                                                      u16* __restrict__ out,
                                                      int R, int Ccols,
                                                      const int* __restrict__ flag) {
  __shared__ u16 tile[32][33];
  int f = *flag;
  int c0 = blockIdx.x * 32, r0 = blockIdx.y * 32;
  int lx = threadIdx.x & 31, ly = threadIdx.x >> 5;
#pragma unroll
  for (int i = 0; i < 32; i += 8) {
    size_t idx = (size_t)(r0 + ly + i) * Ccols + c0 + lx;
    tile[ly + i][lx] = f ? f2b(((const float*)in)[idx]) : ((const u16*)in)[idx];
  }
  __syncthreads();
#pragma unroll
  for (int i = 0; i < 32; i += 8)
    out[(size_t)(c0 + ly + i) * R + r0 + lx] = tile[lx][ly + i];
}

// V half of KV [4096][4096] -> Vt[b][d][s]  ([2][2048][2048])
__global__ __launch_bounds__(256) void transpose_v(const u16* __restrict__ KV,
                                                   u16* __restrict__ Vt) {
  __shared__ u16 tile[32][33];
  int b = blockIdx.z;
  int d0 = blockIdx.x * 32, s0 = blockIdx.y * 32;
  int lx = threadIdx.x & 31, ly = threadIdx.x >> 5;
  const u16* src = KV + ((size_t)(b * 2048 + s0)) * 4096 + 2048 + d0;
#pragma unroll
  for (int i = 0; i < 32; i += 8)
    tile[ly + i][lx] = src[(size_t)(ly + i) * 4096 + lx];
  __syncthreads();
  u16* dst = Vt + ((size_t)(b * 2048 + d0)) * 2048 + s0;
#pragma unroll
  for (int i = 0; i < 32; i += 8)
    dst[(size_t)(ly + i) * 2048 + lx] = tile[lx][ly + i];
}

// ---------------------------------------------------------------------------
// NT GEMM (m97 structure, proven round 2) — used for Q and O projections
// where 256^2 tiling would leave half the CUs idle (grid 128 < 256 CUs).
// ---------------------------------------------------------------------------
__global__ __launch_bounds__(256) void gemm_nt(const u16* __restrict__ A,
                                               const u16* __restrict__ Bm,
                                               void* __restrict__ Cv,
                                               int M, int N, int K,
                                               const int* __restrict__ flag,
                                               int flag_mode) {
  __shared__ u16 Ash[128 * 64];
  __shared__ u16 Bsh[128 * 64];
  int tid = threadIdx.x, w = tid >> 6, lane = tid & 63;
  int quad = lane >> 4, l15 = lane & 15;
  int m0 = blockIdx.y * 128, n0 = blockIdx.x * 128;
  int wm = (w & 1) * 64, wn = (w >> 1) * 64;
  int f32out = flag_mode ? *flag : 0;

  floatx4 acc[4][4];
#pragma unroll
  for (int i = 0; i < 4; ++i)
#pragma unroll
    for (int j = 0; j < 4; ++j) acc[i][j] = floatx4{0.f, 0.f, 0.f, 0.f};

  int srow = lane >> 3;
  int gch = (lane & 7) ^ srow;
  const u16* Ag = A + (size_t)(m0 + w * 32 + srow) * K + gch * 8;
  const u16* Bg = Bm + (size_t)(n0 + w * 32 + srow) * K + gch * 8;

  for (int k0 = 0; k0 < K; k0 += 64) {
    __syncthreads();
#pragma unroll
    for (int t = 0; t < 4; ++t) {
      gl_lds16(Ag + (size_t)t * 8 * K + k0, (void*)(Ash + (w * 32 + t * 8) * 64));
      gl_lds16(Bg + (size_t)t * 8 * K + k0, (void*)(Bsh + (w * 32 + t * 8) * 64));
    }
    __syncthreads();
#pragma unroll
    for (int kk = 0; kk < 2; ++kk) {
      int c = kk * 4 + quad;
      short8 af[4], bf[4];
#pragma unroll
      for (int i = 0; i < 4; ++i) {
        int m = wm + 16 * i + l15;
        af[i] = *(const short8*)(Ash + m * 64 + ((c ^ (m & 7)) << 3));
        int n = wn + 16 * i + l15;
        bf[i] = *(const short8*)(Bsh + n * 64 + ((c ^ (n & 7)) << 3));
      }
#pragma unroll
      for (int i = 0; i < 4; ++i)
#pragma unroll
        for (int j = 0; j < 4; ++j) acc[i][j] = MFMA16(af[i], bf[j], acc[i][j]);
    }
  }

#pragma unroll
  for (int i = 0; i < 4; ++i)
#pragma unroll
    for (int r = 0; r < 4; ++r) {
      int row = m0 + wm + 16 * i + quad * 4 + r;
      if (f32out) {
        float* cp = (float*)Cv + (size_t)row * N + n0 + wn + l15;
#pragma unroll
        for (int j = 0; j < 4; ++j) cp[16 * j] = acc[i][j][r];
      } else {
        u16* cp = (u16*)Cv + (size_t)row * N + n0 + wn + l15;
#pragma unroll
        for (int j = 0; j < 4; ++j) cp[16 * j] = f2b(acc[i][j][r]);
      }
    }
}

// ---------------------------------------------------------------------------
// 8-phase 256x256 NT GEMM (m201 template) — KV projection only (grid 256).
// Phases split by (mh-half x kk): reads 8/8/4/4 ds_read_b128, 16 MFMA each.
// One half-tile (2 gl_lds) staged per phase; vmcnt(6) at tile top only.
// ---------------------------------------------------------------------------
__global__ __launch_bounds__(512, 2) void gemm8(const u16* __restrict__ A,
                                                const u16* __restrict__ Bm,
                                                void* __restrict__ Cv,
                                                int M, int N, int K,
                                                const int* __restrict__ flag,
                                                int flag_mode) {
  __shared__ u16 Ash[2 * 256 * 64];
  __shared__ u16 Bsh[2 * 256 * 64];
  int tid = threadIdx.x, w = tid >> 6, lane = tid & 63;
  int quad = lane >> 4, l15 = lane & 15;
  int wr = w >> 2, wc = w & 3;
  int wm = wr * 128, wn = wc * 64;
  int m0 = blockIdx.y * 256, n0 = blockIdx.x * 256;
  int f32out = flag_mode ? *flag : 0;
  const int NT = K >> 6;

  int srow8 = lane >> 3;
  int gch = (lane & 7) ^ srow8;
  const u16* Ag = A + (size_t)(m0 + w * 8 + srow8) * K + gch * 8;
  const u16* Bg = Bm + (size_t)(n0 + w * 8 + srow8) * K + gch * 8;
  int ldsrow = w * 8;  // wave-uniform LDS row base; lane*16B added by HW

  floatx4 acc[8][4];
#pragma unroll
  for (int i = 0; i < 8; ++i)
#pragma unroll
    for (int j = 0; j < 4; ++j) acc[i][j] = floatx4{0.f, 0.f, 0.f, 0.f};

  int ch0 = ((quad ^ (l15 & 7)) << 3);        // kk=0 chunk byte-> u16 offset
  int ch1 = (((4 + quad) ^ (l15 & 7)) << 3);  // kk=1

  auto stage = [&](int qi) {
    int tau = qi >> 2;
    int tc = tau < NT ? tau : NT - 1;  // clamp keeps vmcnt counts exact
    int hh = qi & 3;                   // 0:B0 1:B1 2:A0 3:A1
    int half = (hh & 1) * 128;
    int sbuf = (tau & 1) * (256 * 64);
    size_t kof = (size_t)tc * 64;
    if (hh < 2) {
      gl_lds16(Bg + (size_t)half * K + kof,
               (void*)(Bsh + sbuf + (half + ldsrow) * 64));
      gl_lds16(Bg + (size_t)(half + 64) * K + kof,
               (void*)(Bsh + sbuf + (half + 64 + ldsrow) * 64));
    } else {
      gl_lds16(Ag + (size_t)half * K + kof,
               (void*)(Ash + sbuf + (half + ldsrow) * 64));
      gl_lds16(Ag + (size_t)(half + 64) * K + kof,
               (void*)(Ash + sbuf + (half + 64 + ldsrow) * 64));
    }
  };

  // Prologue: tile0 fully + 3 half-tiles of tile1 -> 3 half-tiles in flight.
  stage(0); stage(1); stage(2); stage(3);
  __asm__ volatile("s_waitcnt vmcnt(4)" ::: "memory");
  stage(4); stage(5); stage(6);
  __asm__ volatile("s_waitcnt vmcnt(6)" ::: "memory");
  __builtin_amdgcn_s_barrier();

  for (int t = 0; t < NT; ++t) {
    u16* As = Ash + (t & 1) * (256 * 64);
    u16* Bs = Bsh + (t & 1) * (256 * 64);
    if (t) {
      __asm__ volatile("s_waitcnt vmcnt(6)" ::: "memory");
      __builtin_amdgcn_s_barrier();
    }
    int qb = 7 + 4 * t;
    short8 bf[8], af0[8], af1[8];

    // ---- P0: read af0-kk0 + bf-kk0 (8 reads); MFMA mh0 x kk0 (16) ----
#pragma unroll
    for (int j = 0; j < 4; ++j) {
      int n = wn + 16 * j + l15;
      bf[2 * j] = *(const short8*)(Bs + n * 64 + ch0);
    }
#pragma unroll
    for (int i = 0; i < 4; ++i) {
      int m = wm + 16 * i + l15;
      af0[2 * i] = *(const short8*)(As + m * 64 + ch0);
    }
    stage(qb);
    __builtin_amdgcn_s_barrier();
    __asm__ volatile("s_waitcnt lgkmcnt(0)" ::: "memory");
    __builtin_amdgcn_sched_barrier(0);
    __builtin_amdgcn_s_setprio(1);
#pragma unroll
    for (int i = 0; i < 4; ++i)
#pragma unroll
      for (int j = 0; j < 4; ++j)
        acc[i][j] = MFMA16(af0[2 * i], bf[2 * j], acc[i][j]);
    __builtin_amdgcn_s_setprio(0);
    __builtin_amdgcn_s_barrier();

    // ---- P1: read af0-kk1 + bf-kk1 (8 reads); MFMA mh0 x kk1 (16) ----
#pragma unroll
    for (int j = 0; j < 4; ++j) {
      int n = wn + 16 * j + l15;
      bf[2 * j + 1] = *(const short8*)(Bs + n * 64 + ch1);
    }
#pragma unroll
    for (int i = 0; i < 4; ++i) {
      int m = wm + 16 * i + l15;
      af0[2 * i + 1] = *(const short8*)(As + m * 64 + ch1);
    }
    stage(qb + 1);
    __builtin_amdgcn_s_barrier();
    __asm__ volatile("s_waitcnt lgkmcnt(0)" ::: "memory");
    __builtin_amdgcn_sched_barrier(0);
    __builtin_amdgcn_s_setprio(1);
#pragma unroll
    for (int i = 0; i < 4; ++i)
#pragma unroll
      for (int j = 0; j < 4; ++j)
        acc[i][j] = MFMA16(af0[2 * i + 1], bf[2 * j + 1], acc[i][j]);
    __builtin_amdgcn_s_setprio(0);
    __builtin_amdgcn_s_barrier();

    // ---- P2: read af1-kk0 (4 reads); MFMA mh1 x kk0 (16) ----
#pragma unroll
    for (int i = 0; i < 4; ++i) {
      int m = wm + 64 + 16 * i + l15;
      af1[2 * i] = *(const short8*)(As + m * 64 + ch0);
    }
    stage(qb + 2);
    __builtin_amdgcn_s_barrier();
    __asm__ volatile("s_waitcnt lgkmcnt(0)" ::: "memory");
    __builtin_amdgcn_sched_barrier(0);
    __builtin_amdgcn_s_setprio(1);
#pragma unroll
    for (int i = 0; i < 4; ++i)
#pragma unroll
      for (int j = 0; j < 4; ++j)
        acc[4 + i][j] = MFMA16(af1[2 * i], bf[2 * j], acc[4 + i][j]);
    __builtin_amdgcn_s_setprio(0);
    __builtin_amdgcn_s_barrier();

    // ---- P3: read af1-kk1 (4 reads); MFMA mh1 x kk1 (16) ----
#pragma unroll
    for (int i = 0; i < 4; ++i) {
      int m = wm + 64 + 16 * i + l15;
      af1[2 * i + 1] = *(const short8*)(As + m * 64 + ch1);
    }
    stage(qb + 3);
    __builtin_amdgcn_s_barrier();
    __asm__ volatile("s_waitcnt lgkmcnt(0)" ::: "memory");
    __builtin_amdgcn_sched_barrier(0);
    __builtin_amdgcn_s_setprio(1);
#pragma unroll
    for (int i = 0; i < 4; ++i)
#pragma unroll
      for (int j = 0; j < 4; ++j)
        acc[4 + i][j] = MFMA16(af1[2 * i + 1], bf[2 * j + 1], acc[4 + i][j]);
    __builtin_amdgcn_s_setprio(0);
    __builtin_amdgcn_s_barrier();
  }

  // Epilogue (same C/D mapping as proven gemm_nt).
#pragma unroll
  for (int i = 0; i < 8; ++i)
#pragma unroll
    for (int r = 0; r < 4; ++r) {
      int row = m0 + wm + 16 * i + quad * 4 + r;
      if (f32out) {
        float* cp = (float*)Cv + (size_t)row * N + n0 + wn + l15;
#pragma unroll
        for (int j = 0; j < 4; ++j) cp[16 * j] = acc[i][j][r];
      } else {
        u16* cp = (u16*)Cv + (size_t)row * N + n0 + wn + l15;
#pragma unroll
        for (int j = 0; j < 4; ++j) cp[16 * j] = f2b(acc[i][j][r]);
      }
    }
}

// ---------------------------------------------------------------------------
// RoPE in-place; Q additionally scaled by 1/sqrt(dh) (folded from attention).
// ---------------------------------------------------------------------------
__global__ __launch_bounds__(256) void rope_kernel(u16* __restrict__ Q,
                                                   u16* __restrict__ KV) {
  const float scale = 0.08838834764831845f;  // 1/sqrt(128)
  int idx = blockIdx.x * 256 + threadIdx.x;
  int tok = idx >> 10;
  int rem = idx & 1023;
  int h = rem >> 6, i = rem & 63;
  int pos = tok & 2047;
  float f = __powf(10000.0f, -(float)(2 * i) * (1.0f / 128.0f));
  float ang = (float)pos * f;
  float s, c;
  sincosf(ang, &s, &c);

  size_t qb = (size_t)tok * 2048 + h * 128 + i;
  float q1 = b2f(Q[qb]), q2 = b2f(Q[qb + 64]);
  Q[qb] = f2b((q1 * c - q2 * s) * scale);
  Q[qb + 64] = f2b((q2 * c + q1 * s) * scale);

  size_t kb = (size_t)tok * 4096 + h * 128 + i;
  float k1 = b2f(KV[kb]), k2 = b2f(KV[kb + 64]);
  KV[kb] = f2b(k1 * c - k2 * s);
  KV[kb + 64] = f2b(k2 * c + k1 * s);
}

// ---------------------------------------------------------------------------
// Flash attention v6: v5 + (a) double-buffered K/V staging — stage(t+1)
// issued BEFORE compute(t), ONE __syncthreads per k-tile (drains the
// in-flight gl_lds that had the whole compute phase to land); (b) P-write
// swizzle made quad-disjoint: sw = (m&3)^(2*(m>>2)) spreads the 8 chunks
// written per instruction across all 32 banks (v5's m&7 collided quads
// {0,2} and {1,3}: 4.3M SQ_LDS_BANK_CONFLICT). LDS 80K, still 1 block/CU.
// ---------------------------------------------------------------------------
__global__ __launch_bounds__(512, 1) void flash_attn(const u16* __restrict__ Q,
                                                     const u16* __restrict__ KV,
                                                     const u16* __restrict__ Vt,
                                                     u16* __restrict__ O) {
  const int S = 2048, D = 2048, KVld = 4096;
  int bh = blockIdx.x;    // 0..31
  int pair = blockIdx.y;  // 0..7
  int b = bh >> 4, h = bh & 15;
  int tid = threadIdx.x, w = tid >> 6, lane = tid & 63;
  int quad = lane >> 4, l15 = lane & 15;

  const u16* Qb = Q + (size_t)(b * S) * D + h * 128;
  const u16* Kb = KV + (size_t)(b * S) * KVld + h * 128;
  const u16* Vtb = Vt + ((size_t)(b * 2048 + h * 128)) * S;

  __shared__ u16 Ksh[2][64 * 128];  // [buf][krow][d], chunk ^= krow&7
  __shared__ u16 Vsh[2][128 * 64];  // [buf][d][k],   chunk ^= d&7
  __shared__ u16 Psh[8][16 * 64];   // per-wave P, chunk ^= (m&3)^(2*(m>>2))

  // stage K tile [64][128] + V^T tile [128][64] for k-tile kt into buf
  auto stage_kv = [&](int kt, int buf) {
    int kb = kt * 64;
#pragma unroll
    for (int tt = 0; tt < 2; ++tt) {
      int r0 = w * 8 + tt * 4;
      int row = r0 + quad;
      int g = (l15 & 8) | ((l15 & 7) ^ (row & 7));
      gl_lds16(Kb + (size_t)(kb + row) * KVld + g * 8,
               (void*)(Ksh[buf] + r0 * 128));
    }
#pragma unroll
    for (int tt = 0; tt < 2; ++tt) {
      int d0 = w * 16 + tt * 8;
      int d = d0 + (lane >> 3);
      int g = (lane & 7) ^ (d & 7);
      gl_lds16(Vtb + (size_t)d * S + kb + g * 8, (void*)(Vsh[buf] + d0 * 64));
    }
  };

  for (int pi = 0; pi < 2; ++pi) {
    int qt = pi ? (15 - pair) : pair;
    int q0 = qt * 128;
    int qw = q0 + w * 16;  // this wave's 16 q-rows

    short8 qf[4];
    {
      const u16* qp = Qb + (size_t)(qw + l15) * D + quad * 8;
#pragma unroll
      for (int kk = 0; kk < 4; ++kk) qf[kk] = *(const short8*)(qp + kk * 32);
    }

    floatx4 o[8];
#pragma unroll
    for (int t = 0; t < 8; ++t) o[t] = floatx4{0.f, 0.f, 0.f, 0.f};
    float mrow[4], lrow[4];
#pragma unroll
    for (int r = 0; r < 4; ++r) { mrow[r] = -1e30f; lrow[r] = 0.f; }

    int nk = 2 * qt + 2;
    // prologue: stage k-tile 0 into buf 0
    stage_kv(0, 0);
    __syncthreads();

    for (int kt = 0; kt < nk; ++kt) {
      int kb = kt * 64;
      int cur = kt & 1;
      // prefetch next k-tile into the other buffer (hidden under compute)
      if (kt + 1 < nk) stage_kv(kt + 1, cur ^ 1);

      if (kb <= qw + 15) {  // wave has at least one unmasked row
        const u16* Kc = Ksh[cur];
        const u16* Vc = Vsh[cur];
        // --- QK^T: 4n x 4ksteps = 16 MFMA ---
        floatx4 sc[4];
#pragma unroll
        for (int nf = 0; nf < 4; ++nf) sc[nf] = floatx4{0.f, 0.f, 0.f, 0.f};
#pragma unroll
        for (int kk = 0; kk < 4; ++kk) {
          int c = kk * 4 + quad;
          short8 kf[4];
#pragma unroll
          for (int nf = 0; nf < 4; ++nf) {
            int n = nf * 16 + l15;
            int pc = (c & 8) | ((c & 7) ^ (n & 7));
            kf[nf] = *(const short8*)(Kc + n * 128 + pc * 8);
          }
#pragma unroll
          for (int nf = 0; nf < 4; ++nf) sc[nf] = MFMA16(qf[kk], kf[nf], sc[nf]);
        }

        // --- online softmax (1/sqrt(dh) pre-folded into Q) ---
        bool masked = (kb + 63 > qw);
        floatx4 alv;
#pragma unroll
        for (int r = 0; r < 4; ++r) {
          int qg = qw + quad * 4 + r;
          float v0 = sc[0][r], v1 = sc[1][r];
          float v2 = sc[2][r], v3 = sc[3][r];
          if (masked) {
            v0 = (kb + l15 <= qg) ? v0 : -1e30f;
            v1 = (kb + 16 + l15 <= qg) ? v1 : -1e30f;
            v2 = (kb + 32 + l15 <= qg) ? v2 : -1e30f;
            v3 = (kb + 48 + l15 <= qg) ? v3 : -1e30f;
          }
          float mx = max16(fmaxf(fmaxf(v0, v1), fmaxf(v2, v3)));
          float mn = fmaxf(mrow[r], mx);
          float al = __expf(mrow[r] - mn);
          mrow[r] = mn;
          float p0 = __expf(v0 - mn), p1 = __expf(v1 - mn);
          float p2 = __expf(v2 - mn), p3 = __expf(v3 - mn);
          float rs = sum16((p0 + p1) + (p2 + p3));
          lrow[r] = lrow[r] * al + rs;
          alv[r] = al;
          int m_ = quad * 4 + r;
          int sw = (m_ & 3) ^ ((m_ >> 2) << 1);  // quad-disjoint swizzle
          int cb = l15 >> 3, e = l15 & 7;
          u16* pr = Psh[w] + m_ * 64;
          pr[(((0 + cb) ^ sw) << 3) + e] = f2b(p0);
          pr[(((2 + cb) ^ sw) << 3) + e] = f2b(p1);
          pr[(((4 + cb) ^ sw) << 3) + e] = f2b(p2);
          pr[(((6 + cb) ^ sw) << 3) + e] = f2b(p3);
        }
#pragma unroll
        for (int t = 0; t < 8; ++t) o[t] *= alv;
        __asm__ volatile("s_waitcnt lgkmcnt(0)" ::: "memory");

        // --- PV: 8d x 2ksteps = 16 MFMA ---
#pragma unroll
        for (int ks = 0; ks < 2; ++ks) {
          int c = ks * 4 + quad;
          int psw = (l15 & 3) ^ ((l15 >> 2) << 1);  // matches write swizzle
          short8 pf = *(const short8*)(Psh[w] + l15 * 64 + ((c ^ psw) << 3));
#pragma unroll
          for (int t = 0; t < 8; ++t) {
            int d = t * 16 + l15;
            short8 vf = *(const short8*)(Vc + d * 64 + ((c ^ (d & 7)) << 3));
            o[t] = MFMA16(pf, vf, o[t]);
          }
        }
      }
      // drains this wave's prefetch gl_lds (vmcnt) + joins waves; next tile
      // ready on the other buffer.
      __syncthreads();
    }

    // epilogue
#pragma unroll
    for (int r = 0; r < 4; ++r) {
      float inv = 1.0f / lrow[r];
      int qg = qw + quad * 4 + r;
      u16* op = O + (size_t)(b * S + qg) * D + h * 128;
#pragma unroll
      for (int t = 0; t < 8; ++t) op[t * 16 + l15] = f2b(o[t][r] * inv);
    }
  }
}

// ---------------------------------------------------------------------------
// Launch. ws (u16 after 64-elem flag pad):
//   xb 8.4M | Wbuf 8.4M (wq -> wkvT -> Vt -> wo) | Qb 8.4M | KVb 16.8M
//   AO aliases xb. Total ~84 MB.
// ---------------------------------------------------------------------------
extern "C" void kernel_launch(void* const* d_in, const int* in_sizes, int n_in,
                              void* d_out, int out_size, void* d_ws, size_t ws_size,
                              hipStream_t stream) {
  const void* x = d_in[0];
  const void* wq = d_in[1];
  const void* wkv = d_in[2];
  const void* wo = d_in[3];

  int* flag = (int*)d_ws;
  u16* xb = (u16*)d_ws + 64;
  u16* Wbuf = xb + (size_t)8388608;
  u16* Qb = Wbuf + (size_t)8388608;
  u16* KVb = Qb + (size_t)8388608;
  u16* AO = xb;  // x dead after KV projection

  detect_f32<<<1, 256, 0, stream>>>((const u16*)x, flag);
  convert_in8<<<4096, 256, 0, stream>>>(x, xb, 1048576, flag);
  convert_in8<<<2048, 256, 0, stream>>>(wq, Wbuf, 524288, flag);
  gemm_nt<<<dim3(16, 32), 256, 0, stream>>>(xb, Wbuf, Qb, 4096, 2048, 2048, flag, 0);
  transpose_conv<<<dim3(128, 64), 256, 0, stream>>>(wkv, Wbuf, 2048, 4096, flag);
  gemm8<<<dim3(16, 16), 512, 0, stream>>>(xb, Wbuf, KVb, 4096, 4096, 2048, flag, 0);
  transpose_v<<<dim3(64, 64, 2), 256, 0, stream>>>(KVb, Wbuf);  // Wbuf := Vt
  rope_kernel<<<16384, 256, 0, stream>>>(Qb, KVb);
  flash_attn<<<dim3(32, 8), 512, 0, stream>>>(Qb, KVb, Wbuf, AO);
  convert_in8<<<2048, 256, 0, stream>>>(wo, Wbuf, 524288, flag);
  gemm_nt<<<dim3(16, 32), 256, 0, stream>>>(AO, Wbuf, d_out, 4096, 2048, 2048, flag, 1);
}